// Round 2
// baseline (410.500 us; speedup 1.0000x reference)
//
#include <hip/hip_runtime.h>
#include <hip/hip_bf16.h>
#include <stdint.h>

// Problem constants: x (8,4096,1024) f32, weight (1024,1024) f32, bias (1024,)
#define NXK 1024   // K = nx
#define NFN 1024   // N = nf
#define EPSQ 0.01f

typedef __bf16 bf16x8 __attribute__((ext_vector_type(8)));
typedef float f32x4 __attribute__((ext_vector_type(4)));

#define AS1(p) ((const __attribute__((address_space(1))) void*)(p))
#define AS3(p) ((__attribute__((address_space(3))) void*)(p))

// smallest power of two >= m, for positive normal m. Matches exp2(ceil(log2(m))).
__device__ __forceinline__ float p2ceil(float m) {
    unsigned u = __float_as_uint(m);
    if ((u & 0x7fffffu) == 0) return m;               // exact power of 2
    return __uint_as_float((((u >> 23) & 0xffu) + 1u) << 23);
}

__device__ __forceinline__ unsigned short f2bf(float f) {
    __bf16 h = (__bf16)f;   // values are exactly representable in bf16
    return __builtin_bit_cast(unsigned short, h);
}

// ---------------------------------------------------------------------------
// Kernel 1: per-column max|X| via uint-bit atomicMax (|x| >= 0 so bit-order
// == float order). Block covers RPB rows x 1024 cols; thread t owns 4 cols.
// ---------------------------------------------------------------------------
#define RPB 32
__global__ __launch_bounds__(256) void colmax_kernel(const float* __restrict__ X,
                                                     unsigned int* __restrict__ cmax) {
    const int t = threadIdx.x;
    const size_t r0 = (size_t)blockIdx.x * RPB;
    const float4* Xv = (const float4*)X;
    float m0 = 0.f, m1 = 0.f, m2 = 0.f, m3 = 0.f;
#pragma unroll 8
    for (int i = 0; i < RPB; ++i) {
        float4 v = Xv[(r0 + i) * (NXK / 4) + t];
        m0 = fmaxf(m0, fabsf(v.x));
        m1 = fmaxf(m1, fabsf(v.y));
        m2 = fmaxf(m2, fabsf(v.z));
        m3 = fmaxf(m3, fabsf(v.w));
    }
    atomicMax(&cmax[4 * t + 0], __float_as_uint(m0));
    atomicMax(&cmax[4 * t + 1], __float_as_uint(m1));
    atomicMax(&cmax[4 * t + 2], __float_as_uint(m2));
    atomicMax(&cmax[4 * t + 3], __float_as_uint(m3));
}

// ---------------------------------------------------------------------------
// Kernel 2: wave-per-row quantize+dequant -> bf16. 4 rows/block, no LDS, no
// __syncthreads. Lane owns 16 cols as 4 float4s at [lane + 64c] (1KB/wave
// contiguous per load). TRANSPOSE=1 stores Q^T for the weight (B^T GEMM).
// ---------------------------------------------------------------------------
template <int TRANSPOSE>
__global__ __launch_bounds__(256) void rowquant_kernel(const float* __restrict__ X,
                                                       const unsigned int* __restrict__ cmaxbits,
                                                       unsigned short* __restrict__ Q) {
    const int wave = threadIdx.x >> 6, lane = threadIdx.x & 63;
    const int m = blockIdx.x * 4 + wave;
    const float4* Xr = (const float4*)(X + (size_t)m * NXK);
    const uint4* Cb = (const uint4*)cmaxbits;

    float r[16], sc[16];
    float amax = 0.f;
#pragma unroll
    for (int c = 0; c < 4; ++c) {
        const float4 v = Xr[lane + 64 * c];
        const uint4 cb = Cb[lane + 64 * c];
        sc[4 * c + 0] = p2ceil(fmaxf(__uint_as_float(cb.x), EPSQ));
        sc[4 * c + 1] = p2ceil(fmaxf(__uint_as_float(cb.y), EPSQ));
        sc[4 * c + 2] = p2ceil(fmaxf(__uint_as_float(cb.z), EPSQ));
        sc[4 * c + 3] = p2ceil(fmaxf(__uint_as_float(cb.w), EPSQ));
        r[4 * c + 0] = v.x / sc[4 * c + 0];          // exact: power-of-2 divide
        r[4 * c + 1] = v.y / sc[4 * c + 1];
        r[4 * c + 2] = v.z / sc[4 * c + 2];
        r[4 * c + 3] = v.w / sc[4 * c + 3];
        amax = fmaxf(amax, fmaxf(fmaxf(fabsf(r[4 * c + 0]), fabsf(r[4 * c + 1])),
                                 fmaxf(fabsf(r[4 * c + 2]), fabsf(r[4 * c + 3]))));
    }
#pragma unroll
    for (int s = 1; s < 64; s <<= 1) amax = fmaxf(amax, __shfl_xor(amax, s, 64));

    const float srow = p2ceil(fmaxf(amax, EPSQ));
    const float inv = 128.0f / srow;                 // exact power of 2
    const float rs = srow * 0.0078125f;              // srow/128, exact
#pragma unroll
    for (int c = 0; c < 4; ++c) {
        // q = clip(rint(r*128/srow), -128, 127); rintf == RNE == jnp.round
        const float q0 = fminf(fmaxf(rintf(r[4 * c + 0] * inv), -128.0f), 127.0f);
        const float q1 = fminf(fmaxf(rintf(r[4 * c + 1] * inv), -128.0f), 127.0f);
        const float q2 = fminf(fmaxf(rintf(r[4 * c + 2] * inv), -128.0f), 127.0f);
        const float q3 = fminf(fmaxf(rintf(r[4 * c + 3] * inv), -128.0f), 127.0f);
        if (TRANSPOSE) {
            Q[(size_t)(4 * (lane + 64 * c) + 0) * NXK + m] = f2bf(q0 * (sc[4 * c + 0] * rs));
            Q[(size_t)(4 * (lane + 64 * c) + 1) * NXK + m] = f2bf(q1 * (sc[4 * c + 1] * rs));
            Q[(size_t)(4 * (lane + 64 * c) + 2) * NXK + m] = f2bf(q2 * (sc[4 * c + 2] * rs));
            Q[(size_t)(4 * (lane + 64 * c) + 3) * NXK + m] = f2bf(q3 * (sc[4 * c + 3] * rs));
        } else {
            ushort4 o;
            o.x = f2bf(q0 * (sc[4 * c + 0] * rs));
            o.y = f2bf(q1 * (sc[4 * c + 1] * rs));
            o.z = f2bf(q2 * (sc[4 * c + 2] * rs));
            o.w = f2bf(q3 * (sc[4 * c + 3] * rs));
            ((ushort4*)(Q + (size_t)m * NXK))[lane + 64 * c] = o;
        }
    }
}

// ---------------------------------------------------------------------------
// Kernel 3: bf16 GEMM, m97 structure (128x128 tile, BK=32, 4 waves, 4x4
// 16x16x32 frags, global_load_lds width-16) + T1 bijective XCD swizzle so
// each XCD owns contiguous M-panels (A-panel fetched by exactly one XCD).
// ---------------------------------------------------------------------------
#define GX (NFN / 128)   // N-tiles = 8
__global__ __launch_bounds__(256) void gemm_kernel(const unsigned short* __restrict__ A,
                                                   const unsigned short* __restrict__ BT,
                                                   const float* __restrict__ bias,
                                                   float* __restrict__ C, int M) {
    constexpr int K = NXK, N = NFN;
    __shared__ unsigned short As[128][32];   // 8 KB
    __shared__ unsigned short Bs[128][32];   // 8 KB

    const int tid = threadIdx.x;
    const int wave = tid >> 6, lane = tid & 63;
    const int wr = wave >> 1, wc = wave & 1;

    // T1: bijective XCD swizzle (m204 formula). HW: linear id % 8 -> XCD.
    const int nwg = GX * (M / 128);
    int lin = blockIdx.y * GX + blockIdx.x;
    {
        const int q = nwg >> 3, r = nwg & 7;
        const int xcd = lin & 7, idx = lin >> 3;
        lin = (xcd < r ? xcd * (q + 1) : r * (q + 1) + (xcd - r) * q) + idx;
    }
    const int bm = (lin / GX) * 128, bn = (lin % GX) * 128;

    f32x4 acc[4][4] = {};

    const int strow = wave * 32 + (lane >> 2);
    const int stcol = (lane & 3) * 8;
    const unsigned short* gA = A + (size_t)(bm + strow) * K + stcol;
    const unsigned short* gB = BT + (size_t)(bn + strow) * K + stcol;
    unsigned short* lA0 = &As[wave * 32][0];
    unsigned short* lA1 = &As[wave * 32 + 16][0];
    unsigned short* lB0 = &Bs[wave * 32][0];
    unsigned short* lB1 = &Bs[wave * 32 + 16][0];

    for (int k0 = 0; k0 < K; k0 += 32) {
        __builtin_amdgcn_global_load_lds(AS1(gA + k0),          AS3(lA0), 16, 0, 0);
        __builtin_amdgcn_global_load_lds(AS1(gA + 16 * K + k0), AS3(lA1), 16, 0, 0);
        __builtin_amdgcn_global_load_lds(AS1(gB + k0),          AS3(lB0), 16, 0, 0);
        __builtin_amdgcn_global_load_lds(AS1(gB + 16 * K + k0), AS3(lB1), 16, 0, 0);
        asm volatile("s_waitcnt vmcnt(0)" ::: "memory");
        __syncthreads();

        bf16x8 af[4], bf[4];
#pragma unroll
        for (int i = 0; i < 4; ++i) {
            af[i] = *(const bf16x8*)&As[wr * 64 + i * 16 + (lane & 15)][(lane >> 4) * 8];
            bf[i] = *(const bf16x8*)&Bs[wc * 64 + i * 16 + (lane & 15)][(lane >> 4) * 8];
        }
#pragma unroll
        for (int mi = 0; mi < 4; ++mi)
#pragma unroll
            for (int ni = 0; ni < 4; ++ni)
                acc[mi][ni] = __builtin_amdgcn_mfma_f32_16x16x32_bf16(af[mi], bf[ni], acc[mi][ni], 0, 0, 0);
        __syncthreads();
    }

    // Epilogue: C/D layout col=lane&15, row=(lane>>4)*4+j  [m89-verified]
#pragma unroll
    for (int mi = 0; mi < 4; ++mi) {
#pragma unroll
        for (int ni = 0; ni < 4; ++ni) {
            const int col = bn + wc * 64 + ni * 16 + (lane & 15);
            const float bv = bias[col];
#pragma unroll
            for (int j = 0; j < 4; ++j) {
                const int row = bm + wr * 64 + mi * 16 + (lane >> 4) * 4 + j;
                C[(size_t)row * N + col] = acc[mi][ni][j] + bv;
            }
        }
    }
}

// ---------------------------------------------------------------------------
extern "C" void kernel_launch(void* const* d_in, const int* in_sizes, int n_in,
                              void* d_out, int out_size, void* d_ws, size_t ws_size,
                              hipStream_t stream) {
    const float* x    = (const float*)d_in[0];
    const float* w    = (const float*)d_in[1];
    const float* bias = (const float*)d_in[2];
    float* out = (float*)d_out;
    const int M = in_sizes[0] / NXK;   // 32768

    // workspace: xq (M*K bf16) | wqT (N*K bf16) | colmax_x (1024) | colmax_w (1024)
    char* ws = (char*)d_ws;
    unsigned short* xq = (unsigned short*)ws;
    size_t off = (size_t)M * NXK * sizeof(unsigned short);
    unsigned short* wqT = (unsigned short*)(ws + off);
    off += (size_t)NFN * NXK * sizeof(unsigned short);
    unsigned int* cmx = (unsigned int*)(ws + off);
    unsigned int* cmw = cmx + NXK;

    hipMemsetAsync(cmx, 0, (NXK + NFN) * sizeof(unsigned int), stream);

    colmax_kernel<<<M / RPB, 256, 0, stream>>>(x, cmx);
    colmax_kernel<<<NXK / RPB, 256, 0, stream>>>(w, cmw);
    rowquant_kernel<0><<<M / 4, 256, 0, stream>>>(x, cmx, xq);
    rowquant_kernel<1><<<NXK / 4, 256, 0, stream>>>(w, cmw, wqT);
    gemm_kernel<<<dim3(GX, M / 128), 256, 0, stream>>>(xq, wqT, bias, out, M);
}

// Round 3
// 382.636 us; speedup vs baseline: 1.0728x; 1.0728x over previous
//
#include <hip/hip_runtime.h>
#include <hip/hip_bf16.h>
#include <stdint.h>

// Problem constants: x (8,4096,1024) f32, weight (1024,1024) f32, bias (1024,)
#define NXK 1024   // K = nx
#define NFN 1024   // N = nf
#define EPSQ 0.01f

typedef __bf16 bf16x8 __attribute__((ext_vector_type(8)));
typedef float f32x4 __attribute__((ext_vector_type(4)));

#define AS1(p) ((const __attribute__((address_space(1))) void*)(p))
#define AS3(p) ((__attribute__((address_space(3))) void*)(p))

// smallest power of two >= m, for positive normal m. Matches exp2(ceil(log2(m))).
__device__ __forceinline__ float p2ceil(float m) {
    unsigned u = __float_as_uint(m);
    if ((u & 0x7fffffu) == 0) return m;               // exact power of 2
    return __uint_as_float((((u >> 23) & 0xffu) + 1u) << 23);
}

__device__ __forceinline__ unsigned short f2bf(float f) {
    __bf16 h = (__bf16)f;   // values are exactly representable in bf16
    return __builtin_bit_cast(unsigned short, h);
}

// ---------------------------------------------------------------------------
// Kernel 1a: per-column partial max|X| over RPB rows -> pmax[block][1024].
// NO atomics (R2 showed 1M atomicMax onto 1024 addrs = 104us stall).
// ---------------------------------------------------------------------------
#define RPB 32
__global__ __launch_bounds__(256) void colmax_part_kernel(const float* __restrict__ X,
                                                          float* __restrict__ pmax) {
    const int t = threadIdx.x;
    const size_t r0 = (size_t)blockIdx.x * RPB;
    const float4* Xv = (const float4*)X;
    float m0 = 0.f, m1 = 0.f, m2 = 0.f, m3 = 0.f;
#pragma unroll 8
    for (int i = 0; i < RPB; ++i) {
        float4 v = Xv[(r0 + i) * (NXK / 4) + t];
        m0 = fmaxf(m0, fabsf(v.x));
        m1 = fmaxf(m1, fabsf(v.y));
        m2 = fmaxf(m2, fabsf(v.z));
        m3 = fmaxf(m3, fabsf(v.w));
    }
    float4 o; o.x = m0; o.y = m1; o.z = m2; o.w = m3;
    ((float4*)(pmax + (size_t)blockIdx.x * NXK))[t] = o;
}

// ---------------------------------------------------------------------------
// Kernel 1b: reduce partials over blocks-axis, emit column SCALE directly:
// cscale[c] = p2ceil(max(colmax, eps)). 32 blocks x 32 cols each.
// ---------------------------------------------------------------------------
__global__ __launch_bounds__(256) void colmax_reduce_kernel(const float* __restrict__ pmax,
                                                            int npart,
                                                            float* __restrict__ cscale) {
    __shared__ float red[8][32];
    const int t = threadIdx.x;
    const int c = blockIdx.x * 32 + (t & 31);
    const int chunk = t >> 5;                  // 0..7
    const int per = npart >> 3;                // npart/8
    float m = 0.f;
    for (int r = chunk * per; r < (chunk + 1) * per; ++r)
        m = fmaxf(m, pmax[(size_t)r * NXK + c]);
    red[chunk][t & 31] = m;
    __syncthreads();
    if (t < 32) {
        float v = red[0][t];
#pragma unroll
        for (int i = 1; i < 8; ++i) v = fmaxf(v, red[i][t]);
        cscale[blockIdx.x * 32 + t] = p2ceil(fmaxf(v, EPSQ));
    }
}

// ---------------------------------------------------------------------------
// Kernel 1c (weight only, 1024 rows): atomic colmax — 32 blocks -> only 32
// atomics per address, negligible.
// ---------------------------------------------------------------------------
__global__ __launch_bounds__(256) void colmax_atomic_kernel(const float* __restrict__ X,
                                                            unsigned int* __restrict__ cmax) {
    const int t = threadIdx.x;
    const size_t r0 = (size_t)blockIdx.x * RPB;
    const float4* Xv = (const float4*)X;
    float m0 = 0.f, m1 = 0.f, m2 = 0.f, m3 = 0.f;
#pragma unroll 8
    for (int i = 0; i < RPB; ++i) {
        float4 v = Xv[(r0 + i) * (NXK / 4) + t];
        m0 = fmaxf(m0, fabsf(v.x));
        m1 = fmaxf(m1, fabsf(v.y));
        m2 = fmaxf(m2, fabsf(v.z));
        m3 = fmaxf(m3, fabsf(v.w));
    }
    atomicMax(&cmax[4 * t + 0], __float_as_uint(m0));
    atomicMax(&cmax[4 * t + 1], __float_as_uint(m1));
    atomicMax(&cmax[4 * t + 2], __float_as_uint(m2));
    atomicMax(&cmax[4 * t + 3], __float_as_uint(m3));
}

// ---------------------------------------------------------------------------
// Kernel 2: wave-per-row quantize+dequant -> bf16. 4 rows/block, no LDS/sync.
// Lane owns 16 cols as 4 float4s at [lane + 64c]. TRANSPOSE=1 stores Q^T.
// PRESCALED=1: col input is precomputed float scales; else uint maxbits.
// ---------------------------------------------------------------------------
template <int TRANSPOSE, int PRESCALED>
__global__ __launch_bounds__(256) void rowquant_kernel(const float* __restrict__ X,
                                                       const void* __restrict__ colinfo,
                                                       unsigned short* __restrict__ Q) {
    const int wave = threadIdx.x >> 6, lane = threadIdx.x & 63;
    const int m = blockIdx.x * 4 + wave;
    const float4* Xr = (const float4*)(X + (size_t)m * NXK);

    float r[16], sc[16];
    float amax = 0.f;
#pragma unroll
    for (int c = 0; c < 4; ++c) {
        const float4 v = Xr[lane + 64 * c];
        if (PRESCALED) {
            const float4 s = ((const float4*)colinfo)[lane + 64 * c];
            sc[4 * c + 0] = s.x; sc[4 * c + 1] = s.y;
            sc[4 * c + 2] = s.z; sc[4 * c + 3] = s.w;
        } else {
            const uint4 cb = ((const uint4*)colinfo)[lane + 64 * c];
            sc[4 * c + 0] = p2ceil(fmaxf(__uint_as_float(cb.x), EPSQ));
            sc[4 * c + 1] = p2ceil(fmaxf(__uint_as_float(cb.y), EPSQ));
            sc[4 * c + 2] = p2ceil(fmaxf(__uint_as_float(cb.z), EPSQ));
            sc[4 * c + 3] = p2ceil(fmaxf(__uint_as_float(cb.w), EPSQ));
        }
        r[4 * c + 0] = v.x / sc[4 * c + 0];          // exact: power-of-2 divide
        r[4 * c + 1] = v.y / sc[4 * c + 1];
        r[4 * c + 2] = v.z / sc[4 * c + 2];
        r[4 * c + 3] = v.w / sc[4 * c + 3];
        amax = fmaxf(amax, fmaxf(fmaxf(fabsf(r[4 * c + 0]), fabsf(r[4 * c + 1])),
                                 fmaxf(fabsf(r[4 * c + 2]), fabsf(r[4 * c + 3]))));
    }
#pragma unroll
    for (int s = 1; s < 64; s <<= 1) amax = fmaxf(amax, __shfl_xor(amax, s, 64));

    const float srow = p2ceil(fmaxf(amax, EPSQ));
    const float inv = 128.0f / srow;                 // exact power of 2
    const float rs = srow * 0.0078125f;              // srow/128, exact
#pragma unroll
    for (int c = 0; c < 4; ++c) {
        // q = clip(rint(r*128/srow), -128, 127); rintf == RNE == jnp.round
        const float q0 = fminf(fmaxf(rintf(r[4 * c + 0] * inv), -128.0f), 127.0f);
        const float q1 = fminf(fmaxf(rintf(r[4 * c + 1] * inv), -128.0f), 127.0f);
        const float q2 = fminf(fmaxf(rintf(r[4 * c + 2] * inv), -128.0f), 127.0f);
        const float q3 = fminf(fmaxf(rintf(r[4 * c + 3] * inv), -128.0f), 127.0f);
        if (TRANSPOSE) {
            Q[(size_t)(4 * (lane + 64 * c) + 0) * NXK + m] = f2bf(q0 * (sc[4 * c + 0] * rs));
            Q[(size_t)(4 * (lane + 64 * c) + 1) * NXK + m] = f2bf(q1 * (sc[4 * c + 1] * rs));
            Q[(size_t)(4 * (lane + 64 * c) + 2) * NXK + m] = f2bf(q2 * (sc[4 * c + 2] * rs));
            Q[(size_t)(4 * (lane + 64 * c) + 3) * NXK + m] = f2bf(q3 * (sc[4 * c + 3] * rs));
        } else {
            ushort4 o;
            o.x = f2bf(q0 * (sc[4 * c + 0] * rs));
            o.y = f2bf(q1 * (sc[4 * c + 1] * rs));
            o.z = f2bf(q2 * (sc[4 * c + 2] * rs));
            o.w = f2bf(q3 * (sc[4 * c + 3] * rs));
            ((ushort4*)(Q + (size_t)m * NXK))[lane + 64 * c] = o;
        }
    }
}

// ---------------------------------------------------------------------------
// Kernel 3: bf16 GEMM, m97 structure (128x128 tile, BK=32, 4 waves, 4x4
// 16x16x32 frags, global_load_lds width-16) + T1 bijective XCD swizzle.
// Unchanged from R2 (verified bit-exact; FETCH 57 MB = near-ideal).
// ---------------------------------------------------------------------------
#define GX (NFN / 128)   // N-tiles = 8
__global__ __launch_bounds__(256) void gemm_kernel(const unsigned short* __restrict__ A,
                                                   const unsigned short* __restrict__ BT,
                                                   const float* __restrict__ bias,
                                                   float* __restrict__ C, int M) {
    constexpr int K = NXK, N = NFN;
    __shared__ unsigned short As[128][32];   // 8 KB
    __shared__ unsigned short Bs[128][32];   // 8 KB

    const int tid = threadIdx.x;
    const int wave = tid >> 6, lane = tid & 63;
    const int wr = wave >> 1, wc = wave & 1;

    // T1: bijective XCD swizzle (m204). HW: linear id % 8 -> XCD.
    const int nwg = GX * (M / 128);
    int lin = blockIdx.y * GX + blockIdx.x;
    {
        const int q = nwg >> 3, r = nwg & 7;
        const int xcd = lin & 7, idx = lin >> 3;
        lin = (xcd < r ? xcd * (q + 1) : r * (q + 1) + (xcd - r) * q) + idx;
    }
    const int bm = (lin / GX) * 128, bn = (lin % GX) * 128;

    f32x4 acc[4][4] = {};

    const int strow = wave * 32 + (lane >> 2);
    const int stcol = (lane & 3) * 8;
    const unsigned short* gA = A + (size_t)(bm + strow) * K + stcol;
    const unsigned short* gB = BT + (size_t)(bn + strow) * K + stcol;
    unsigned short* lA0 = &As[wave * 32][0];
    unsigned short* lA1 = &As[wave * 32 + 16][0];
    unsigned short* lB0 = &Bs[wave * 32][0];
    unsigned short* lB1 = &Bs[wave * 32 + 16][0];

    for (int k0 = 0; k0 < K; k0 += 32) {
        __builtin_amdgcn_global_load_lds(AS1(gA + k0),          AS3(lA0), 16, 0, 0);
        __builtin_amdgcn_global_load_lds(AS1(gA + 16 * K + k0), AS3(lA1), 16, 0, 0);
        __builtin_amdgcn_global_load_lds(AS1(gB + k0),          AS3(lB0), 16, 0, 0);
        __builtin_amdgcn_global_load_lds(AS1(gB + 16 * K + k0), AS3(lB1), 16, 0, 0);
        asm volatile("s_waitcnt vmcnt(0)" ::: "memory");
        __syncthreads();

        bf16x8 af[4], bf[4];
#pragma unroll
        for (int i = 0; i < 4; ++i) {
            af[i] = *(const bf16x8*)&As[wr * 64 + i * 16 + (lane & 15)][(lane >> 4) * 8];
            bf[i] = *(const bf16x8*)&Bs[wc * 64 + i * 16 + (lane & 15)][(lane >> 4) * 8];
        }
#pragma unroll
        for (int mi = 0; mi < 4; ++mi)
#pragma unroll
            for (int ni = 0; ni < 4; ++ni)
                acc[mi][ni] = __builtin_amdgcn_mfma_f32_16x16x32_bf16(af[mi], bf[ni], acc[mi][ni], 0, 0, 0);
        __syncthreads();
    }

    // Epilogue: C/D layout col=lane&15, row=(lane>>4)*4+j  [m89-verified]
#pragma unroll
    for (int mi = 0; mi < 4; ++mi) {
#pragma unroll
        for (int ni = 0; ni < 4; ++ni) {
            const int col = bn + wc * 64 + ni * 16 + (lane & 15);
            const float bv = bias[col];
#pragma unroll
            for (int j = 0; j < 4; ++j) {
                const int row = bm + wr * 64 + mi * 16 + (lane >> 4) * 4 + j;
                C[(size_t)row * N + col] = acc[mi][ni][j] + bv;
            }
        }
    }
}

// ---------------------------------------------------------------------------
extern "C" void kernel_launch(void* const* d_in, const int* in_sizes, int n_in,
                              void* d_out, int out_size, void* d_ws, size_t ws_size,
                              hipStream_t stream) {
    const float* x    = (const float*)d_in[0];
    const float* w    = (const float*)d_in[1];
    const float* bias = (const float*)d_in[2];
    float* out = (float*)d_out;
    const int M = in_sizes[0] / NXK;   // 32768
    const int NPART = M / RPB;         // 1024 partial rows

    // workspace: xq | wqT | pmax (NPART*1024 f32) | cscale (1024 f32) | cmw (1024 u32)
    char* ws = (char*)d_ws;
    unsigned short* xq = (unsigned short*)ws;
    size_t off = (size_t)M * NXK * sizeof(unsigned short);
    unsigned short* wqT = (unsigned short*)(ws + off);
    off += (size_t)NFN * NXK * sizeof(unsigned short);
    float* pmax = (float*)(ws + off);
    off += (size_t)NPART * NXK * sizeof(float);
    float* cscale = (float*)(ws + off);
    off += NXK * sizeof(float);
    unsigned int* cmw = (unsigned int*)(ws + off);

    hipMemsetAsync(cmw, 0, NFN * sizeof(unsigned int), stream);

    colmax_part_kernel<<<NPART, 256, 0, stream>>>(x, pmax);
    colmax_atomic_kernel<<<NXK / RPB, 256, 0, stream>>>(w, cmw);
    colmax_reduce_kernel<<<NXK / 32, 256, 0, stream>>>(pmax, NPART, cscale);
    rowquant_kernel<0, 1><<<M / 4, 256, 0, stream>>>(x, cscale, xq);
    rowquant_kernel<1, 0><<<NXK / 4, 256, 0, stream>>>(w, cmw, wqT);
    gemm_kernel<<<dim3(GX, M / 128), 256, 0, stream>>>(xq, wqT, bias, out, M);
}

// Round 4
// 362.447 us; speedup vs baseline: 1.1326x; 1.0557x over previous
//
#include <hip/hip_runtime.h>
#include <hip/hip_bf16.h>
#include <stdint.h>

// Problem constants: x (8,4096,1024) f32, weight (1024,1024) f32, bias (1024,)
#define NXK 1024   // K = nx
#define NFN 1024   // N = nf
#define EPSQ 0.01f

typedef __bf16 bf16x8 __attribute__((ext_vector_type(8)));
typedef float f32x4 __attribute__((ext_vector_type(4)));

#define AS1(p) ((const __attribute__((address_space(1))) void*)(p))
#define AS3(p) ((__attribute__((address_space(3))) void*)(p))

__device__ __forceinline__ float p2ceil(float m) {
    unsigned u = __float_as_uint(m);
    if ((u & 0x7fffffu) == 0) return m;               // exact power of 2
    return __uint_as_float((((u >> 23) & 0xffu) + 1u) << 23);
}

__device__ __forceinline__ unsigned short f2bf(float f) {
    __bf16 h = (__bf16)f;   // values are exactly representable in bf16
    return __builtin_bit_cast(unsigned short, h);
}

// ---------------------------------------------------------------------------
// Pre-pass kernels (unchanged from R3 — verified bit-exact)
// ---------------------------------------------------------------------------
#define RPB 32
__global__ __launch_bounds__(256) void colmax_part_kernel(const float* __restrict__ X,
                                                          float* __restrict__ pmax) {
    const int t = threadIdx.x;
    const size_t r0 = (size_t)blockIdx.x * RPB;
    const float4* Xv = (const float4*)X;
    float m0 = 0.f, m1 = 0.f, m2 = 0.f, m3 = 0.f;
#pragma unroll 8
    for (int i = 0; i < RPB; ++i) {
        float4 v = Xv[(r0 + i) * (NXK / 4) + t];
        m0 = fmaxf(m0, fabsf(v.x));
        m1 = fmaxf(m1, fabsf(v.y));
        m2 = fmaxf(m2, fabsf(v.z));
        m3 = fmaxf(m3, fabsf(v.w));
    }
    float4 o; o.x = m0; o.y = m1; o.z = m2; o.w = m3;
    ((float4*)(pmax + (size_t)blockIdx.x * NXK))[t] = o;
}

__global__ __launch_bounds__(256) void colmax_reduce_kernel(const float* __restrict__ pmax,
                                                            int npart,
                                                            float* __restrict__ cscale) {
    __shared__ float red[8][32];
    const int t = threadIdx.x;
    const int c = blockIdx.x * 32 + (t & 31);
    const int chunk = t >> 5;
    const int per = npart >> 3;
    float m = 0.f;
    for (int r = chunk * per; r < (chunk + 1) * per; ++r)
        m = fmaxf(m, pmax[(size_t)r * NXK + c]);
    red[chunk][t & 31] = m;
    __syncthreads();
    if (t < 32) {
        float v = red[0][t];
#pragma unroll
        for (int i = 1; i < 8; ++i) v = fmaxf(v, red[i][t]);
        cscale[blockIdx.x * 32 + t] = p2ceil(fmaxf(v, EPSQ));
    }
}

__global__ __launch_bounds__(256) void colmax_atomic_kernel(const float* __restrict__ X,
                                                            unsigned int* __restrict__ cmax) {
    const int t = threadIdx.x;
    const size_t r0 = (size_t)blockIdx.x * RPB;
    const float4* Xv = (const float4*)X;
    float m0 = 0.f, m1 = 0.f, m2 = 0.f, m3 = 0.f;
#pragma unroll 8
    for (int i = 0; i < RPB; ++i) {
        float4 v = Xv[(r0 + i) * (NXK / 4) + t];
        m0 = fmaxf(m0, fabsf(v.x));
        m1 = fmaxf(m1, fabsf(v.y));
        m2 = fmaxf(m2, fabsf(v.z));
        m3 = fmaxf(m3, fabsf(v.w));
    }
    atomicMax(&cmax[4 * t + 0], __float_as_uint(m0));
    atomicMax(&cmax[4 * t + 1], __float_as_uint(m1));
    atomicMax(&cmax[4 * t + 2], __float_as_uint(m2));
    atomicMax(&cmax[4 * t + 3], __float_as_uint(m3));
}

template <int TRANSPOSE, int PRESCALED>
__global__ __launch_bounds__(256) void rowquant_kernel(const float* __restrict__ X,
                                                       const void* __restrict__ colinfo,
                                                       unsigned short* __restrict__ Q) {
    const int wave = threadIdx.x >> 6, lane = threadIdx.x & 63;
    const int m = blockIdx.x * 4 + wave;
    const float4* Xr = (const float4*)(X + (size_t)m * NXK);

    float r[16], sc[16];
    float amax = 0.f;
#pragma unroll
    for (int c = 0; c < 4; ++c) {
        const float4 v = Xr[lane + 64 * c];
        if (PRESCALED) {
            const float4 s = ((const float4*)colinfo)[lane + 64 * c];
            sc[4 * c + 0] = s.x; sc[4 * c + 1] = s.y;
            sc[4 * c + 2] = s.z; sc[4 * c + 3] = s.w;
        } else {
            const uint4 cb = ((const uint4*)colinfo)[lane + 64 * c];
            sc[4 * c + 0] = p2ceil(fmaxf(__uint_as_float(cb.x), EPSQ));
            sc[4 * c + 1] = p2ceil(fmaxf(__uint_as_float(cb.y), EPSQ));
            sc[4 * c + 2] = p2ceil(fmaxf(__uint_as_float(cb.z), EPSQ));
            sc[4 * c + 3] = p2ceil(fmaxf(__uint_as_float(cb.w), EPSQ));
        }
        r[4 * c + 0] = v.x / sc[4 * c + 0];
        r[4 * c + 1] = v.y / sc[4 * c + 1];
        r[4 * c + 2] = v.z / sc[4 * c + 2];
        r[4 * c + 3] = v.w / sc[4 * c + 3];
        amax = fmaxf(amax, fmaxf(fmaxf(fabsf(r[4 * c + 0]), fabsf(r[4 * c + 1])),
                                 fmaxf(fabsf(r[4 * c + 2]), fabsf(r[4 * c + 3]))));
    }
#pragma unroll
    for (int s = 1; s < 64; s <<= 1) amax = fmaxf(amax, __shfl_xor(amax, s, 64));

    const float srow = p2ceil(fmaxf(amax, EPSQ));
    const float inv = 128.0f / srow;
    const float rs = srow * 0.0078125f;
#pragma unroll
    for (int c = 0; c < 4; ++c) {
        const float q0 = fminf(fmaxf(rintf(r[4 * c + 0] * inv), -128.0f), 127.0f);
        const float q1 = fminf(fmaxf(rintf(r[4 * c + 1] * inv), -128.0f), 127.0f);
        const float q2 = fminf(fmaxf(rintf(r[4 * c + 2] * inv), -128.0f), 127.0f);
        const float q3 = fminf(fmaxf(rintf(r[4 * c + 3] * inv), -128.0f), 127.0f);
        if (TRANSPOSE) {
            Q[(size_t)(4 * (lane + 64 * c) + 0) * NXK + m] = f2bf(q0 * (sc[4 * c + 0] * rs));
            Q[(size_t)(4 * (lane + 64 * c) + 1) * NXK + m] = f2bf(q1 * (sc[4 * c + 1] * rs));
            Q[(size_t)(4 * (lane + 64 * c) + 2) * NXK + m] = f2bf(q2 * (sc[4 * c + 2] * rs));
            Q[(size_t)(4 * (lane + 64 * c) + 3) * NXK + m] = f2bf(q3 * (sc[4 * c + 3] * rs));
        } else {
            ushort4 o;
            o.x = f2bf(q0 * (sc[4 * c + 0] * rs));
            o.y = f2bf(q1 * (sc[4 * c + 1] * rs));
            o.z = f2bf(q2 * (sc[4 * c + 2] * rs));
            o.w = f2bf(q3 * (sc[4 * c + 3] * rs));
            ((ushort4*)(Q + (size_t)m * NXK))[lane + 64 * c] = o;
        }
    }
}

// ---------------------------------------------------------------------------
// 8-phase 256x256 GEMM (T1+T2+T3+T4+T5). BK=64, 8 waves (2M x 4N), 512 thr.
// LDS: A 4 half-slots x 16KB + B 4 half-slots x 16KB = 128 KiB (dynamic).
// Half-tile = 128 rows x 64 K-cols bf16, row stride 128B, XOR swizzle
// byte ^= (row&7)<<4 (both sides: pre-swizzled global src + swizzled ds_read).
// ---------------------------------------------------------------------------
#define BM 256
#define BN 256
#define BKT 64
#define NT (NXK / BKT)   // 16
#define GXT (NFN / BN)   // 4 n-tiles

#define BARRIER() do { asm volatile("" ::: "memory"); __builtin_amdgcn_s_barrier(); asm volatile("" ::: "memory"); } while (0)
#define WAIT_LGKM0() do { asm volatile("s_waitcnt lgkmcnt(0)" ::: "memory"); __builtin_amdgcn_sched_barrier(0); } while (0)
#define WAIT_VM(n) do { asm volatile("s_waitcnt vmcnt(" #n ")" ::: "memory"); __builtin_amdgcn_sched_barrier(0); } while (0)

__device__ __forceinline__ void stage_half(const unsigned short* __restrict__ G,
                                           int gr0, int k0, char* ldsbase, int tid) {
#pragma unroll
    for (int i = 0; i < 2; ++i) {
        const int chunk = i * 512 + tid;           // 0..1023
        const int r = chunk >> 3;                  // 0..127
        const int cb = (chunk & 7) * 16;           // 0..112
        const int scb = cb ^ ((r & 7) << 4);       // inverse swizzle on SOURCE
        const char* src = (const char*)(G + (size_t)(gr0 + r) * NXK + k0) + scb;
        char* dst = ldsbase + (size_t)(i * 512 + (tid & ~63)) * 16;  // wave-uniform; +lane*16 implicit
        __builtin_amdgcn_global_load_lds(AS1(src), AS3(dst), 16, 0, 0);
    }
}

__global__ __launch_bounds__(512, 2) void gemm8_kernel(const unsigned short* __restrict__ A,
                                                       const unsigned short* __restrict__ BT,
                                                       const float* __restrict__ bias,
                                                       float* __restrict__ C, int M) {
    extern __shared__ char smem[];
    char* Alds = smem;             // 4 x 16384
    char* Blds = smem + 65536;     // 4 x 16384

    const int tid = threadIdx.x;
    const int wv = tid >> 6, lane = tid & 63;
    const int wm = wv >> 2, wn = wv & 3;

    // T1 bijective XCD swizzle (nwg % 8 == 0 here: nwg = (M/256)*4 = 512)
    const int nwg = (M / BM) * GXT;
    int lin = blockIdx.x;
    {
        const int q = nwg >> 3;
        lin = (lin & 7) * q + (lin >> 3);
    }
    const int bm = (lin >> 2) * BM;
    const int bn = (lin & 3) * BN;

    // bias regs — force completion so loop vmcnt counts are exact
    float bv[4];
#pragma unroll
    for (int nf = 0; nf < 4; ++nf) bv[nf] = bias[bn + wn * 64 + nf * 16 + (lane & 15)];
    asm volatile("" : "+v"(bv[0]), "+v"(bv[1]), "+v"(bv[2]), "+v"(bv[3]));
    asm volatile("s_waitcnt vmcnt(0)" ::: "memory");

    f32x4 acc[8][4] = {};
    bf16x8 a[4][2], b[2][2][2];

    const int xr = (lane & 7) << 4;
    const int colx0 = ((lane >> 4) * 16) ^ xr;
    const int colx1 = (((lane >> 4) * 16) + 64) ^ xr;
    const int arow = lane & 15;
    const int brow0 = (wn & 1) * 64 + (lane & 15);

#define LOAD_A(mh) do { _Pragma("unroll") for (int mf = 0; mf < 4; ++mf) { \
        const int lr = (mh) * 64 + mf * 16 + arow; \
        a[mf][0] = *(const bf16x8*)(Asl + lr * 128 + colx0); \
        a[mf][1] = *(const bf16x8*)(Asl + lr * 128 + colx1); } } while (0)

#define LOAD_B(nh) do { _Pragma("unroll") for (int nf = 0; nf < 2; ++nf) { \
        const int lr = brow0 + (nh) * 32 + nf * 16; \
        b[nh][nf][0] = *(const bf16x8*)(Bsl + lr * 128 + colx0); \
        b[nh][nf][1] = *(const bf16x8*)(Bsl + lr * 128 + colx1); } } while (0)

#define MFMA_Q(mh, nh) do { \
        __builtin_amdgcn_s_setprio(1); \
        _Pragma("unroll") for (int mf = 0; mf < 4; ++mf) \
        _Pragma("unroll") for (int nf = 0; nf < 2; ++nf) { \
            acc[(mh)*4+mf][(nh)*2+nf] = __builtin_amdgcn_mfma_f32_16x16x32_bf16(a[mf][0], b[nh][nf][0], acc[(mh)*4+mf][(nh)*2+nf], 0, 0, 0); \
            acc[(mh)*4+mf][(nh)*2+nf] = __builtin_amdgcn_mfma_f32_16x16x32_bf16(a[mf][1], b[nh][nf][1], acc[(mh)*4+mf][(nh)*2+nf], 0, 0, 0); } \
        __builtin_amdgcn_s_setprio(0); \
        __builtin_amdgcn_sched_barrier(0); } while (0)

    // Prologue: stage t0{A0,B0,A1,B1}, t1{A0,B0}; wait t0 complete (4 loads left)
    stage_half(A,  bm,       0,   Alds + 0 * 16384, tid);
    stage_half(BT, bn,       0,   Blds + 0 * 16384, tid);
    stage_half(A,  bm + 128, 0,   Alds + 1 * 16384, tid);
    stage_half(BT, bn + 128, 0,   Blds + 1 * 16384, tid);
    stage_half(A,  bm,       BKT, Alds + 2 * 16384, tid);
    stage_half(BT, bn,       BKT, Blds + 2 * 16384, tid);
    WAIT_VM(4);
    BARRIER();

    for (int t = 0; t < NT; ++t) {
        const int sN1 = (2 * t + 3) & 3;     // next tile half1 slot
        const int sT0 = (2 * t) & 3;         // cur tile half0 slot (reused by t+2)
        const char* Asl = Alds + (size_t)(((2 * t) + wm) & 3) * 16384;
        const char* Bsl = Blds + (size_t)(((2 * t) + (wn >> 1)) & 3) * 16384;
        const int k0n = (t + 1) * BKT, k0nn = (t + 2) * BKT;
        const bool p1 = (t + 1) < NT, p2 = (t + 2) < NT;

        // ---- phase 1: quadrant (M0,N0); stage (t+1) A-half1
        LOAD_A(0);
        LOAD_B(0);
        if (p1) stage_half(A, bm + 128, k0n, Alds + sN1 * 16384, tid);
        BARRIER();
        WAIT_LGKM0();
        MFMA_Q(0, 0);
        BARRIER();

        // ---- phase 2: quadrant (M0,N1); stage (t+1) B-half1
        LOAD_B(1);
        if (p1) stage_half(BT, bn + 128, k0n, Blds + sN1 * 16384, tid);
        BARRIER();
        WAIT_LGKM0();
        MFMA_Q(0, 1);
        BARRIER();

        // ---- phase 3: quadrant (M1,N0); stage (t+2) B-half0 (cur B0 slot, reads done)
        LOAD_A(1);
        if (p2) stage_half(BT, bn, k0nn, Blds + sT0 * 16384, tid);
        BARRIER();
        WAIT_LGKM0();
        MFMA_Q(1, 0);
        BARRIER();

        // ---- phase 4: quadrant (M1,N1); stage (t+2) A-half0; tile-boundary wait
        if (p2) stage_half(A, bm, k0nn, Alds + sT0 * 16384, tid);
        BARRIER();
        WAIT_LGKM0();
        MFMA_Q(1, 1);
        if (p2) { WAIT_VM(4); }             // next tile's 8 loads land; 4 stay in flight
        else if (p1) { WAIT_VM(0); }        // tail: drain for last tile
        BARRIER();
    }

    // Epilogue: C/D layout col=lane&15, row=(lane>>4)*4+j  [m89-verified]
#pragma unroll
    for (int mf8 = 0; mf8 < 8; ++mf8) {
#pragma unroll
        for (int nf = 0; nf < 4; ++nf) {
            const int col = bn + wn * 64 + nf * 16 + (lane & 15);
            const size_t rb = (size_t)(bm + wm * 128 + mf8 * 16 + (lane >> 4) * 4) * NFN + col;
#pragma unroll
            for (int j = 0; j < 4; ++j)
                C[rb + (size_t)j * NFN] = acc[mf8][nf][j] + bv[nf];
        }
    }
#undef LOAD_A
#undef LOAD_B
#undef MFMA_Q
}

// ---------------------------------------------------------------------------
extern "C" void kernel_launch(void* const* d_in, const int* in_sizes, int n_in,
                              void* d_out, int out_size, void* d_ws, size_t ws_size,
                              hipStream_t stream) {
    const float* x    = (const float*)d_in[0];
    const float* w    = (const float*)d_in[1];
    const float* bias = (const float*)d_in[2];
    float* out = (float*)d_out;
    const int M = in_sizes[0] / NXK;   // 32768
    const int NPART = M / RPB;         // 1024

    char* ws = (char*)d_ws;
    unsigned short* xq = (unsigned short*)ws;
    size_t off = (size_t)M * NXK * sizeof(unsigned short);
    unsigned short* wqT = (unsigned short*)(ws + off);
    off += (size_t)NFN * NXK * sizeof(unsigned short);
    float* pmax = (float*)(ws + off);
    off += (size_t)NPART * NXK * sizeof(float);
    float* cscale = (float*)(ws + off);
    off += NXK * sizeof(float);
    unsigned int* cmw = (unsigned int*)(ws + off);

    hipFuncSetAttribute((const void*)gemm8_kernel,
                        hipFuncAttributeMaxDynamicSharedMemorySize, 131072);

    hipMemsetAsync(cmw, 0, NFN * sizeof(unsigned int), stream);

    colmax_part_kernel<<<NPART, 256, 0, stream>>>(x, pmax);
    colmax_atomic_kernel<<<NXK / RPB, 256, 0, stream>>>(w, cmw);
    colmax_reduce_kernel<<<NXK / 32, 256, 0, stream>>>(pmax, NPART, cscale);
    rowquant_kernel<0, 1><<<M / 4, 256, 0, stream>>>(x, cscale, xq);
    rowquant_kernel<1, 0><<<NXK / 4, 256, 0, stream>>>(w, cmw, wqT);

    const int nwg = (M / BM) * GXT;    // 512
    gemm8_kernel<<<nwg, 512, 131072, stream>>>(xq, wqT, bias, out, M);
}